// Round 1
// baseline (2806.750 us; speedup 1.0000x reference)
//
#include <hip/hip_runtime.h>
#include <math.h>

#define HID  128
#define EDIM 416
#define CATD 672      // 2*HID + EDIM
#define NN   10000
#define NE   160000
#define TE   64       // edges per block (edge kernel) / nodes per block (node kernel)
#define KT   32       // K tile

__device__ __forceinline__ float silu_f(float x) {
    return x / (1.0f + __expf(-x));
}

// ---------------- LayerNorm: one wave per node ----------------
__global__ __launch_bounds__(256) void ln_kernel(const float* __restrict__ x,
                                                 const float* __restrict__ g,
                                                 const float* __restrict__ b,
                                                 float* __restrict__ xh) {
    int node = blockIdx.x * 4 + (threadIdx.x >> 6);
    int lane = threadIdx.x & 63;
    if (node >= NN) return;
    const float* xr = x + (size_t)node * HID;
    float v0 = xr[lane], v1 = xr[lane + 64];
    float s = v0 + v1;
    #pragma unroll
    for (int off = 1; off < 64; off <<= 1) s += __shfl_xor(s, off);
    float mu = s * (1.0f / HID);
    float d0 = v0 - mu, d1 = v1 - mu;
    float vs = d0 * d0 + d1 * d1;
    #pragma unroll
    for (int off = 1; off < 64; off <<= 1) vs += __shfl_xor(vs, off);
    float rstd = rsqrtf(vs * (1.0f / HID) + 1e-5f);
    float* o = xh + (size_t)node * HID;
    o[lane]      = d0 * rstd * g[lane]      + b[lane];
    o[lane + 64] = d1 * rstd * g[lane + 64] + b[lane + 64];
}

// ---------------- Edge kernel: 64 edges x 128 outs per block ----------------
__global__ __launch_bounds__(256) void edge_kernel(
    const float* __restrict__ xh,
    const float* __restrict__ weight,
    const float* __restrict__ We1, const float* __restrict__ be1,
    const float* __restrict__ We2, const float* __restrict__ be2,
    const float* __restrict__ Wa,  const float* __restrict__ ba,
    const float* __restrict__ Wo,  const float* __restrict__ bo,
    const int* __restrict__ ii, const int* __restrict__ jj,
    float* __restrict__ agg, float* __restrict__ cnt,
    float* __restrict__ edgeh)
{
    __shared__ float catile[TE][KT + 1];     // A K-tile, padded
    __shared__ float wls[KT][HID];           // W K-tile
    __shared__ float mls[TE][HID + 4];       // m1 / m / m_ij staging
    __shared__ int   iis[TE], jjs[TE];
    __shared__ float attv[TE];

    int t  = threadIdx.x;
    int e0 = blockIdx.x * TE;

    if (t < TE) { iis[t] = ii[e0 + t]; jjs[t] = jj[e0 + t]; }
    __syncthreads();

    int ec = t & 15;        // edge slot base (edges ec, ec+16, ec+32, ec+48)
    int og = t >> 4;        // output group -> cols [og*8, og*8+8)
    int o0 = og * 8;

    // ---------- GEMM1: cat(672) @ We1 -> 128 ----------
    float acc[4][8];
    #pragma unroll
    for (int r = 0; r < 4; ++r)
        #pragma unroll
        for (int c = 0; c < 8; ++c) acc[r][c] = 0.f;

    for (int kt = 0; kt < CATD / KT; ++kt) {
        int k0 = kt * KT;
        __syncthreads();
        // A tile: 64 edges x 32 k, 8 elems/thread
        #pragma unroll
        for (int j = 0; j < 8; ++j) {
            int idx = t + j * 256;
            int e = idx >> 5, k = idx & 31;
            int kk = k0 + k;
            float v;
            if (kk < HID)            v = xh[(size_t)iis[e] * HID + kk];
            else if (kk < 2 * HID)   v = xh[(size_t)jjs[e] * HID + (kk - HID)];
            else                     v = weight[(size_t)(e0 + e) * EDIM + (kk - 2 * HID)];
            catile[e][k] = v;
        }
        // W tile: 32 x 128, 16 elems/thread
        #pragma unroll
        for (int j = 0; j < 16; ++j) {
            int idx = t + j * 256;
            int k = idx >> 7, o = idx & 127;
            wls[k][o] = We1[(size_t)(k0 + k) * HID + o];
        }
        __syncthreads();
        #pragma unroll
        for (int k = 0; k < KT; ++k) {
            float a[4], w[8];
            #pragma unroll
            for (int r = 0; r < 4; ++r) a[r] = catile[ec + 16 * r][k];
            #pragma unroll
            for (int c = 0; c < 8; ++c) w[c] = wls[k][o0 + c];
            #pragma unroll
            for (int r = 0; r < 4; ++r)
                #pragma unroll
                for (int c = 0; c < 8; ++c) acc[r][c] += a[r] * w[c];
        }
    }
    // m1 = silu(acc + be1) -> mls
    {
        float bias[8];
        #pragma unroll
        for (int c = 0; c < 8; ++c) bias[c] = be1[o0 + c];
        #pragma unroll
        for (int r = 0; r < 4; ++r)
            #pragma unroll
            for (int c = 0; c < 8; ++c)
                mls[ec + 16 * r][o0 + c] = silu_f(acc[r][c] + bias[c]);
    }

    // ---------- GEMM2: m1(128) @ We2 -> 128 ----------
    float acc2[4][8];
    #pragma unroll
    for (int r = 0; r < 4; ++r)
        #pragma unroll
        for (int c = 0; c < 8; ++c) acc2[r][c] = 0.f;

    for (int kt = 0; kt < HID / KT; ++kt) {
        __syncthreads();   // protects wls reuse and (1st iter) mls writes
        #pragma unroll
        for (int j = 0; j < 16; ++j) {
            int idx = t + j * 256;
            int k = idx >> 7, o = idx & 127;
            wls[k][o] = We2[(size_t)(kt * KT + k) * HID + o];
        }
        __syncthreads();
        #pragma unroll
        for (int k = 0; k < KT; ++k) {
            float a[4], w[8];
            #pragma unroll
            for (int r = 0; r < 4; ++r) a[r] = mls[ec + 16 * r][kt * KT + k];
            #pragma unroll
            for (int c = 0; c < 8; ++c) w[c] = wls[k][o0 + c];
            #pragma unroll
            for (int r = 0; r < 4; ++r)
                #pragma unroll
                for (int c = 0; c < 8; ++c) acc2[r][c] += a[r] * w[c];
        }
    }
    __syncthreads();       // everyone done reading m1 from mls
    float m[4][8];
    {
        float bias[8];
        #pragma unroll
        for (int c = 0; c < 8; ++c) bias[c] = be2[o0 + c];
        #pragma unroll
        for (int r = 0; r < 4; ++r)
            #pragma unroll
            for (int c = 0; c < 8; ++c) {
                m[r][c] = silu_f(acc2[r][c] + bias[c]);
                mls[ec + 16 * r][o0 + c] = m[r][c];
            }
    }
    __syncthreads();

    // ---------- attention: att = silu(m . Wa + ba) ----------
    {
        int ea = t >> 2;          // edge
        int q  = t & 3;           // k quarter
        float s = 0.f;
        #pragma unroll
        for (int k = 0; k < 32; ++k) {
            int kk = q * 32 + k;
            s += mls[ea][kk] * Wa[kk];
        }
        s += __shfl_xor(s, 1);
        s += __shfl_xor(s, 2);
        if (q == 0) attv[ea] = silu_f(s + ba[0]);
    }
    __syncthreads();

    // ---------- m_ij = m * att; aggregate + restage ----------
    float mi[4][8];
    {
        float at[4];
        #pragma unroll
        for (int r = 0; r < 4; ++r) at[r] = attv[ec + 16 * r];
        #pragma unroll
        for (int r = 0; r < 4; ++r)
            #pragma unroll
            for (int c = 0; c < 8; ++c) {
                mi[r][c] = m[r][c] * at[r];
                mls[ec + 16 * r][o0 + c] = mi[r][c];
            }
    }
    // mean-aggregation (sum + count) via atomics
    #pragma unroll
    for (int r = 0; r < 4; ++r) {
        int node = iis[ec + 16 * r];
        #pragma unroll
        for (int c = 0; c < 8; ++c)
            atomicAdd(&agg[(size_t)node * HID + o0 + c], mi[r][c]);
    }
    if (t < TE) atomicAdd(&cnt[iis[t]], 1.0f);

    // ---------- GEMM3: m_ij(128) @ Wo -> 416, epilogue ----------
    for (int nc = 0; nc < 4; ++nc) {
        int n0 = nc * 128;
        int ncols = EDIM - n0; if (ncols > 128) ncols = 128;
        float acc3[4][8];
        #pragma unroll
        for (int r = 0; r < 4; ++r)
            #pragma unroll
            for (int c = 0; c < 8; ++c) acc3[r][c] = 0.f;

        for (int kt = 0; kt < HID / KT; ++kt) {
            __syncthreads();
            #pragma unroll
            for (int j = 0; j < 16; ++j) {
                int idx = t + j * 256;
                int k = idx >> 7, o = idx & 127;
                wls[k][o] = (o < ncols) ? Wo[(size_t)(kt * KT + k) * EDIM + n0 + o] : 0.f;
            }
            __syncthreads();
            #pragma unroll
            for (int k = 0; k < KT; ++k) {
                float a[4], w[8];
                #pragma unroll
                for (int r = 0; r < 4; ++r) a[r] = mls[ec + 16 * r][kt * KT + k];
                #pragma unroll
                for (int c = 0; c < 8; ++c) w[c] = wls[k][o0 + c];
                #pragma unroll
                for (int r = 0; r < 4; ++r)
                    #pragma unroll
                    for (int c = 0; c < 8; ++c) acc3[r][c] += a[r] * w[c];
            }
        }
        if (o0 < ncols) {
            float bias[8];
            #pragma unroll
            for (int c = 0; c < 8; ++c) bias[c] = bo[n0 + o0 + c];
            #pragma unroll
            for (int r = 0; r < 4; ++r) {
                size_t row = (size_t)(e0 + ec + 16 * r) * EDIM + n0 + o0;
                #pragma unroll
                for (int c = 0; c < 8; ++c)
                    edgeh[row + c] = weight[row + c] + silu_f(acc3[r][c] + bias[c]);
            }
        }
    }
}

// ---------------- Node kernel: 64 nodes x 128 outs per block ----------------
__global__ __launch_bounds__(256) void node_kernel(
    const float* __restrict__ xh,
    const float* __restrict__ agg, const float* __restrict__ cnt,
    const float* __restrict__ Wn1, const float* __restrict__ bn1,
    const float* __restrict__ Wn2, const float* __restrict__ bn2,
    float* __restrict__ out)
{
    __shared__ float catile[TE][KT + 1];
    __shared__ float wls[KT][HID];
    __shared__ float mls[TE][HID + 4];
    __shared__ float inv[TE];

    int t   = threadIdx.x;
    int n0b = blockIdx.x * TE;

    if (t < TE) {
        int n = n0b + t;
        float c = (n < NN) ? cnt[n] : 1.f;
        inv[t] = (c == 0.f) ? 1.f : 1.f / c;
    }

    int ec = t & 15, og = t >> 4, o0 = og * 8;

    // GEMM1: [xh | agg/cnt] (256) @ Wn1 -> 128
    float acc[4][8];
    #pragma unroll
    for (int r = 0; r < 4; ++r)
        #pragma unroll
        for (int c = 0; c < 8; ++c) acc[r][c] = 0.f;

    for (int kt = 0; kt < (2 * HID) / KT; ++kt) {
        int k0 = kt * KT;
        __syncthreads();
        #pragma unroll
        for (int j = 0; j < 8; ++j) {
            int idx = t + j * 256;
            int e = idx >> 5, k = idx & 31;
            int kk = k0 + k;
            int n = n0b + e;
            float v = 0.f;
            if (n < NN) {
                if (kk < HID) v = xh[(size_t)n * HID + kk];
                else          v = agg[(size_t)n * HID + (kk - HID)] * inv[e];
            }
            catile[e][k] = v;
        }
        #pragma unroll
        for (int j = 0; j < 16; ++j) {
            int idx = t + j * 256;
            int k = idx >> 7, o = idx & 127;
            wls[k][o] = Wn1[(size_t)(k0 + k) * HID + o];
        }
        __syncthreads();
        #pragma unroll
        for (int k = 0; k < KT; ++k) {
            float a[4], w[8];
            #pragma unroll
            for (int r = 0; r < 4; ++r) a[r] = catile[ec + 16 * r][k];
            #pragma unroll
            for (int c = 0; c < 8; ++c) w[c] = wls[k][o0 + c];
            #pragma unroll
            for (int r = 0; r < 4; ++r)
                #pragma unroll
                for (int c = 0; c < 8; ++c) acc[r][c] += a[r] * w[c];
        }
    }
    {
        float bias[8];
        #pragma unroll
        for (int c = 0; c < 8; ++c) bias[c] = bn1[o0 + c];
        #pragma unroll
        for (int r = 0; r < 4; ++r)
            #pragma unroll
            for (int c = 0; c < 8; ++c)
                mls[ec + 16 * r][o0 + c] = silu_f(acc[r][c] + bias[c]);
    }

    // GEMM2: n1(128) @ Wn2 -> 128
    float acc2[4][8];
    #pragma unroll
    for (int r = 0; r < 4; ++r)
        #pragma unroll
        for (int c = 0; c < 8; ++c) acc2[r][c] = 0.f;

    for (int kt = 0; kt < HID / KT; ++kt) {
        __syncthreads();
        #pragma unroll
        for (int j = 0; j < 16; ++j) {
            int idx = t + j * 256;
            int k = idx >> 7, o = idx & 127;
            wls[k][o] = Wn2[(size_t)(kt * KT + k) * HID + o];
        }
        __syncthreads();
        #pragma unroll
        for (int k = 0; k < KT; ++k) {
            float a[4], w[8];
            #pragma unroll
            for (int r = 0; r < 4; ++r) a[r] = mls[ec + 16 * r][kt * KT + k];
            #pragma unroll
            for (int c = 0; c < 8; ++c) w[c] = wls[k][o0 + c];
            #pragma unroll
            for (int r = 0; r < 4; ++r)
                #pragma unroll
                for (int c = 0; c < 8; ++c) acc2[r][c] += a[r] * w[c];
        }
    }
    {
        float bias[8];
        #pragma unroll
        for (int c = 0; c < 8; ++c) bias[c] = bn2[o0 + c];
        #pragma unroll
        for (int r = 0; r < 4; ++r) {
            int n = n0b + ec + 16 * r;
            if (n < NN) {
                #pragma unroll
                for (int c = 0; c < 8; ++c)
                    out[(size_t)n * HID + o0 + c] =
                        xh[(size_t)n * HID + o0 + c] + silu_f(acc2[r][c] + bias[c]);
            }
        }
    }
}

extern "C" void kernel_launch(void* const* d_in, const int* in_sizes, int n_in,
                              void* d_out, int out_size, void* d_ws, size_t ws_size,
                              hipStream_t stream) {
    (void)in_sizes; (void)n_in; (void)out_size; (void)ws_size;
    const float* x      = (const float*)d_in[0];
    const float* weight = (const float*)d_in[1];
    const float* ln_g   = (const float*)d_in[2];
    const float* ln_b   = (const float*)d_in[3];
    const float* We1    = (const float*)d_in[4];
    const float* be1    = (const float*)d_in[5];
    const float* We2    = (const float*)d_in[6];
    const float* be2    = (const float*)d_in[7];
    const float* Wa     = (const float*)d_in[8];
    const float* ba     = (const float*)d_in[9];
    const float* Wn1    = (const float*)d_in[10];
    const float* bn1    = (const float*)d_in[11];
    const float* Wn2    = (const float*)d_in[12];
    const float* bn2    = (const float*)d_in[13];
    const float* Wo     = (const float*)d_in[14];
    const float* bo     = (const float*)d_in[15];
    const int*   eidx   = (const int*)d_in[16];
    const int* ii = eidx;
    const int* jj = eidx + NE;

    float* xh  = (float*)d_ws;                       // NN*HID
    float* agg = xh + (size_t)NN * HID;              // NN*HID
    float* cnt = agg + (size_t)NN * HID;             // NN

    float* xh_out = (float*)d_out;
    float* edgeh  = xh_out + (size_t)NN * HID;

    hipMemsetAsync(agg, 0, ((size_t)NN * HID + NN) * sizeof(float), stream);
    ln_kernel<<<(NN + 3) / 4, 256, 0, stream>>>(x, ln_g, ln_b, xh);
    edge_kernel<<<NE / TE, 256, 0, stream>>>(xh, weight, We1, be1, We2, be2,
                                             Wa, ba, Wo, bo, ii, jj,
                                             agg, cnt, edgeh);
    node_kernel<<<(NN + TE - 1) / TE, 256, 0, stream>>>(xh, agg, cnt,
                                                        Wn1, bn1, Wn2, bn2, xh_out);
}